// Round 7
// baseline (375.754 us; speedup 1.0000x reference)
//
#include <hip/hip_runtime.h>
#include <hip/hip_bf16.h>

#define BD 4
#define SD 2048
#define DD 512
#define VD 32000
#define NTOK (BD * SD)
#define EPS_L2 1e-12f
#define ROW_BLOCKS (VD / 4)  // one wave per row, 4 waves/block

typedef float f32x4 __attribute__((ext_vector_type(4)));

// ws layout: [ head V int ][ next NTOK int ][ pgw NTOK f32 ][ lossPart 256 f32 ][ done int ]
#define WS_NEXT VD
#define WS_PGW (VD + NTOK)
#define WS_LOSSP (VD + 2 * NTOK)
#define WS_DONE (VD + 2 * NTOK + 256)

// K1 (after a 128KB memset of head to 0xFF): build per-vocab token lists,
// stash p[t,gold] (sign encodes pad), zero loss partials + done counter.
__global__ void __launch_bounds__(256)
build_kernel(const int* __restrict__ gold, const int* __restrict__ mask,
             const float* __restrict__ p, int* __restrict__ head,
             int* __restrict__ next, float* __restrict__ pgw,
             float* __restrict__ lossPart, int* __restrict__ done) {
    int t = blockIdx.x * 256 + threadIdx.x;
    if (blockIdx.x == 0) {
        lossPart[threadIdx.x] = 0.f;
        if (threadIdx.x == 0) *done = 0;
    }
    int g = gold[t];
    next[t] = atomicExch(&head[g], t);
    float pg = p[(size_t)t * VD + g];
    pgw[t] = mask[t] ? -1.f : pg;  // p in [0,1); sign marks pad
}

// K2: one wave per vocab row. Single pass: copy/blend + loss. Last block
// reduces the loss partials (no extra dispatch).
__global__ void __launch_bounds__(256)
row_kernel(const float* __restrict__ x, const float* __restrict__ cache,
           const int* __restrict__ head, const int* __restrict__ next,
           const float* __restrict__ pgw, float* __restrict__ out,
           float* __restrict__ lossPart, int* __restrict__ done) {
    int row = blockIdx.x * 4 + (threadIdx.x >> 6);
    int lane = threadIdx.x & 63;
    const f32x4* cr = (const f32x4*)cache + (size_t)row * (DD / 4);
    f32x4 ca = __builtin_nontemporal_load(cr + lane);
    f32x4 cb = __builtin_nontemporal_load(cr + 64 + lane);
    float* o = out + 1 + (size_t)row * DD;
    int b = lane * 4;
    int t = head[row];

    if (t < 0) {  // untouched row: passthrough copy
        __builtin_nontemporal_store(ca.x, o + b + 0);
        __builtin_nontemporal_store(ca.y, o + b + 1);
        __builtin_nontemporal_store(ca.z, o + b + 2);
        __builtin_nontemporal_store(ca.w, o + b + 3);
        __builtin_nontemporal_store(cb.x, o + 256 + b + 0);
        __builtin_nontemporal_store(cb.y, o + 256 + b + 1);
        __builtin_nontemporal_store(cb.z, o + 256 + b + 2);
        __builtin_nontemporal_store(cb.w, o + 256 + b + 3);
    } else {
        float sc = ca.x * ca.x + ca.y * ca.y + ca.z * ca.z + ca.w * ca.w
                 + cb.x * cb.x + cb.y * cb.y + cb.z * cb.z + cb.w * cb.w;
        #pragma unroll
        for (int off = 32; off; off >>= 1) sc += __shfl_xor(sc, off, 64);
        float rnc = 1.0f / fmaxf(sqrtf(sc), EPS_L2);

        f32x4 aa = {0.f, 0.f, 0.f, 0.f}, ab = {0.f, 0.f, 0.f, 0.f};
        float lossAcc = 0.f;
        int cnt = 0;
        while (t >= 0) {
            int tn = next[t];
            float w = pgw[t];  // broadcast; < 0 means padded
            const f32x4* xr = (const f32x4*)x + (size_t)t * (DD / 4);
            f32x4 xa = __builtin_nontemporal_load(xr + lane);
            f32x4 xb = __builtin_nontemporal_load(xr + 64 + lane);

            float dot = xa.x * ca.x + xa.y * ca.y + xa.z * ca.z + xa.w * ca.w
                      + xb.x * cb.x + xb.y * cb.y + xb.z * cb.z + xb.w * cb.w;
            float sx = xa.x * xa.x + xa.y * xa.y + xa.z * xa.z + xa.w * xa.w
                     + xb.x * xb.x + xb.y * xb.y + xb.z * xb.z + xb.w * xb.w;
            #pragma unroll
            for (int off = 32; off; off >>= 1) {
                dot += __shfl_xor(dot, off, 64);
                sx += __shfl_xor(sx, off, 64);
            }
            cnt++;  // counts include padded tokens (ref semantics)
            if (w >= 0.f) {
                float rnx = 1.0f / fmaxf(sqrtf(sx), EPS_L2);
                lossAcc += 2.f - 2.f * dot * rnx * rnc;
                aa.x += w * xa.x; aa.y += w * xa.y;
                aa.z += w * xa.z; aa.w += w * xa.w;
                ab.x += w * xb.x; ab.y += w * xb.y;
                ab.z += w * xb.z; ab.w += w * xb.w;
            }
            t = tn;
        }

        float m = 0.1f / (float)cnt;
        __builtin_nontemporal_store(0.9f * ca.x + m * aa.x, o + b + 0);
        __builtin_nontemporal_store(0.9f * ca.y + m * aa.y, o + b + 1);
        __builtin_nontemporal_store(0.9f * ca.z + m * aa.z, o + b + 2);
        __builtin_nontemporal_store(0.9f * ca.w + m * aa.w, o + b + 3);
        __builtin_nontemporal_store(0.9f * cb.x + m * ab.x, o + 256 + b + 0);
        __builtin_nontemporal_store(0.9f * cb.y + m * ab.y, o + 256 + b + 1);
        __builtin_nontemporal_store(0.9f * cb.z + m * ab.z, o + 256 + b + 2);
        __builtin_nontemporal_store(0.9f * cb.w + m * ab.w, o + 256 + b + 3);

        if (lane == 0 && lossAcc != 0.f) {
            int wv = (blockIdx.x * 256 + threadIdx.x) >> 6;
            atomicAdd(&lossPart[wv & 255], lossAcc);
        }
    }

    // Last-block-done: final loss reduction without an extra dispatch.
    __shared__ int isLast;
    __syncthreads();
    if (threadIdx.x == 0) {
        __threadfence();
        isLast = (atomicAdd(done, 1) == (int)gridDim.x - 1);
    }
    __syncthreads();
    if (isLast) {
        __shared__ float sm[4];
        float a = atomicAdd(&lossPart[threadIdx.x], 0.f);  // coherent read
        #pragma unroll
        for (int off = 32; off; off >>= 1) a += __shfl_xor(a, off, 64);
        if ((threadIdx.x & 63) == 0) sm[threadIdx.x >> 6] = a;
        __syncthreads();
        if (threadIdx.x == 0) out[0] = sm[0] + sm[1] + sm[2] + sm[3];
    }
}

extern "C" void kernel_launch(void* const* d_in, const int* in_sizes, int n_in,
                              void* d_out, int out_size, void* d_ws, size_t ws_size,
                              hipStream_t stream) {
    const float* x = (const float*)d_in[0];
    const float* p = (const float*)d_in[1];
    const int* gold = (const int*)d_in[2];
    const int* mask = (const int*)d_in[3];
    const float* cache = (const float*)d_in[4];
    float* out = (float*)d_out;
    int* head = (int*)d_ws;
    int* next = head + WS_NEXT;
    float* pgw = (float*)d_ws + WS_PGW;
    float* lossPart = (float*)d_ws + WS_LOSSP;
    int* done = (int*)d_ws + WS_DONE;

    hipMemsetAsync(head, 0xFF, sizeof(int) * VD, stream);  // head = -1
    build_kernel<<<NTOK / 256, 256, 0, stream>>>(gold, mask, p, head, next,
                                                 pgw, lossPart, done);
    row_kernel<<<ROW_BLOCKS, 256, 0, stream>>>(x, cache, head, next, pgw, out,
                                               lossPart, done);
}

// Round 8
// 302.658 us; speedup vs baseline: 1.2415x; 1.2415x over previous
//
#include <hip/hip_runtime.h>
#include <hip/hip_bf16.h>

#define BD 4
#define SD 2048
#define DD 512
#define VD 32000
#define NTOK (BD * SD)
#define EPS_L2 1e-12f
#define ROW_BLOCKS (VD / 4)  // one wave per row, 4 waves/block

// ws layout: [ head V int ][ next NTOK int ][ pgw NTOK f32 ][ lossPart 256 f32 ][ done int ]
#define WS_NEXT VD
#define WS_PGW (VD + NTOK)
#define WS_LOSSP (VD + 2 * NTOK)
#define WS_DONE (VD + 2 * NTOK + 256)

// K1 (after a 128KB memset of head to 0xFF): build per-vocab token lists,
// stash p[t,gold] (sign encodes pad), zero loss partials + done counter.
__global__ void __launch_bounds__(256)
build_kernel(const int* __restrict__ gold, const int* __restrict__ mask,
             const float* __restrict__ p, int* __restrict__ head,
             int* __restrict__ next, float* __restrict__ pgw,
             float* __restrict__ lossPart, int* __restrict__ done) {
    int t = blockIdx.x * 256 + threadIdx.x;
    if (blockIdx.x == 0) {
        lossPart[threadIdx.x] = 0.f;
        if (threadIdx.x == 0) *done = 0;
    }
    int g = gold[t];
    next[t] = atomicExch(&head[g], t);
    float pg = p[(size_t)t * VD + g];
    pgw[t] = mask[t] ? -1.f : pg;  // p in [0,1); sign marks pad
}

// K2: one wave per vocab row. Single pass: copy/blend + loss. Last block
// reduces the loss partials (no extra dispatch). Plain loads/stores only —
// nontemporal scalar stores regressed 9.6x (R7).
__global__ void __launch_bounds__(256)
row_kernel(const float* __restrict__ x, const float* __restrict__ cache,
           const int* __restrict__ head, const int* __restrict__ next,
           const float* __restrict__ pgw, float* __restrict__ out,
           float* __restrict__ lossPart, int* __restrict__ done) {
    int row = blockIdx.x * 4 + (threadIdx.x >> 6);
    int lane = threadIdx.x & 63;
    const float4* cr = (const float4*)cache + (size_t)row * (DD / 4);
    float4 ca = cr[lane], cb = cr[64 + lane];
    float* o = out + 1 + (size_t)row * DD;
    int b = lane * 4;
    int t = head[row];

    if (t < 0) {  // untouched row: passthrough copy
        o[b + 0] = ca.x; o[b + 1] = ca.y; o[b + 2] = ca.z; o[b + 3] = ca.w;
        o[256 + b + 0] = cb.x; o[256 + b + 1] = cb.y;
        o[256 + b + 2] = cb.z; o[256 + b + 3] = cb.w;
    } else {
        float sc = ca.x * ca.x + ca.y * ca.y + ca.z * ca.z + ca.w * ca.w
                 + cb.x * cb.x + cb.y * cb.y + cb.z * cb.z + cb.w * cb.w;
        #pragma unroll
        for (int off = 32; off; off >>= 1) sc += __shfl_xor(sc, off, 64);
        float rnc = 1.0f / fmaxf(sqrtf(sc), EPS_L2);

        float4 aa = {0.f, 0.f, 0.f, 0.f}, ab = {0.f, 0.f, 0.f, 0.f};
        float lossAcc = 0.f;
        int cnt = 0;
        while (t >= 0) {
            int tn = next[t];
            float w = pgw[t];  // broadcast; < 0 means padded
            const float4* xr = (const float4*)x + (size_t)t * (DD / 4);
            float4 xa = xr[lane], xb = xr[64 + lane];

            float dot = xa.x * ca.x + xa.y * ca.y + xa.z * ca.z + xa.w * ca.w
                      + xb.x * cb.x + xb.y * cb.y + xb.z * cb.z + xb.w * cb.w;
            float sx = xa.x * xa.x + xa.y * xa.y + xa.z * xa.z + xa.w * xa.w
                     + xb.x * xb.x + xb.y * xb.y + xb.z * xb.z + xb.w * xb.w;
            #pragma unroll
            for (int off = 32; off; off >>= 1) {
                dot += __shfl_xor(dot, off, 64);
                sx += __shfl_xor(sx, off, 64);
            }
            cnt++;  // counts include padded tokens (ref semantics)
            if (w >= 0.f) {
                float rnx = 1.0f / fmaxf(sqrtf(sx), EPS_L2);
                lossAcc += 2.f - 2.f * dot * rnx * rnc;
                aa.x += w * xa.x; aa.y += w * xa.y;
                aa.z += w * xa.z; aa.w += w * xa.w;
                ab.x += w * xb.x; ab.y += w * xb.y;
                ab.z += w * xb.z; ab.w += w * xb.w;
            }
            t = tn;
        }

        float m = 0.1f / (float)cnt;
        o[b + 0] = 0.9f * ca.x + m * aa.x;
        o[b + 1] = 0.9f * ca.y + m * aa.y;
        o[b + 2] = 0.9f * ca.z + m * aa.z;
        o[b + 3] = 0.9f * ca.w + m * aa.w;
        o[256 + b + 0] = 0.9f * cb.x + m * ab.x;
        o[256 + b + 1] = 0.9f * cb.y + m * ab.y;
        o[256 + b + 2] = 0.9f * cb.z + m * ab.z;
        o[256 + b + 3] = 0.9f * cb.w + m * ab.w;

        if (lane == 0 && lossAcc != 0.f) {
            int wv = (blockIdx.x * 256 + threadIdx.x) >> 6;
            atomicAdd(&lossPart[wv & 255], lossAcc);
        }
    }

    // Last-block-done: final loss reduction without an extra dispatch.
    __shared__ int isLast;
    __syncthreads();
    if (threadIdx.x == 0) {
        __threadfence();
        isLast = (atomicAdd(done, 1) == (int)gridDim.x - 1);
    }
    __syncthreads();
    if (isLast) {
        __shared__ float sm[4];
        float a = atomicAdd(&lossPart[threadIdx.x], 0.f);  // coherent read
        #pragma unroll
        for (int off = 32; off; off >>= 1) a += __shfl_xor(a, off, 64);
        if ((threadIdx.x & 63) == 0) sm[threadIdx.x >> 6] = a;
        __syncthreads();
        if (threadIdx.x == 0) out[0] = sm[0] + sm[1] + sm[2] + sm[3];
    }
}

extern "C" void kernel_launch(void* const* d_in, const int* in_sizes, int n_in,
                              void* d_out, int out_size, void* d_ws, size_t ws_size,
                              hipStream_t stream) {
    const float* x = (const float*)d_in[0];
    const float* p = (const float*)d_in[1];
    const int* gold = (const int*)d_in[2];
    const int* mask = (const int*)d_in[3];
    const float* cache = (const float*)d_in[4];
    float* out = (float*)d_out;
    int* head = (int*)d_ws;
    int* next = head + WS_NEXT;
    float* pgw = (float*)d_ws + WS_PGW;
    float* lossPart = (float*)d_ws + WS_LOSSP;
    int* done = (int*)d_ws + WS_DONE;

    hipMemsetAsync(head, 0xFF, sizeof(int) * VD, stream);  // head = -1
    build_kernel<<<NTOK / 256, 256, 0, stream>>>(gold, mask, p, head, next,
                                                 pgw, lossPart, done);
    row_kernel<<<ROW_BLOCKS, 256, 0, stream>>>(x, cache, head, next, pgw, out,
                                               lossPart, done);
}

// Round 9
// 38.639 us; speedup vs baseline: 9.7248x; 7.8330x over previous
//
#include <hip/hip_runtime.h>
#include <hip/hip_bf16.h>

#define BD 4
#define SD 2048
#define DD 512
#define VD 32000
#define NTOK (BD * SD)
#define EPS_L2 1e-12f
#define ROW_BLOCKS (VD / 4)  // one wave per row, 4 waves/block

// ws layout: [ head V int ][ next NTOK int ][ pgw NTOK f32 ][ lossPart 256 f32 ]
#define WS_NEXT VD
#define WS_PGW (VD + NTOK)
#define WS_LOSSP (VD + 2 * NTOK)

// K1 (after a 128KB memset of head to 0xFF): build per-vocab token lists,
// stash p[t,gold] (sign encodes pad), zero loss partials.
__global__ void __launch_bounds__(256)
build_kernel(const int* __restrict__ gold, const int* __restrict__ mask,
             const float* __restrict__ p, int* __restrict__ head,
             int* __restrict__ next, float* __restrict__ pgw,
             float* __restrict__ lossPart) {
    int t = blockIdx.x * 256 + threadIdx.x;
    if (blockIdx.x == 0) lossPart[threadIdx.x] = 0.f;
    int g = gold[t];
    next[t] = atomicExch(&head[g], t);
    float pg = p[(size_t)t * VD + g];
    pgw[t] = mask[t] ? -1.f : pg;  // p in [0,1); sign marks pad
}

// K2: one wave per vocab row. Single pass: copy/blend + loss.
// NO __threadfence / done-counter here: per-block device-scope fences force
// XCD L2 writeback on gfx950 (R8: 302us vs 39us). Loss reduce is a separate
// tiny dispatch.
__global__ void __launch_bounds__(256)
row_kernel(const float* __restrict__ x, const float* __restrict__ cache,
           const int* __restrict__ head, const int* __restrict__ next,
           const float* __restrict__ pgw, float* __restrict__ out,
           float* __restrict__ lossPart) {
    int row = blockIdx.x * 4 + (threadIdx.x >> 6);
    int lane = threadIdx.x & 63;
    const float4* cr = (const float4*)cache + (size_t)row * (DD / 4);
    float4 ca = cr[lane], cb = cr[64 + lane];
    float* o = out + 1 + (size_t)row * DD;
    int b = lane * 4;
    int t = head[row];

    if (t < 0) {  // untouched row: passthrough copy
        o[b + 0] = ca.x; o[b + 1] = ca.y; o[b + 2] = ca.z; o[b + 3] = ca.w;
        o[256 + b + 0] = cb.x; o[256 + b + 1] = cb.y;
        o[256 + b + 2] = cb.z; o[256 + b + 3] = cb.w;
        return;
    }

    float sc = ca.x * ca.x + ca.y * ca.y + ca.z * ca.z + ca.w * ca.w
             + cb.x * cb.x + cb.y * cb.y + cb.z * cb.z + cb.w * cb.w;
    #pragma unroll
    for (int off = 32; off; off >>= 1) sc += __shfl_xor(sc, off, 64);
    float rnc = 1.0f / fmaxf(sqrtf(sc), EPS_L2);

    float4 aa = {0.f, 0.f, 0.f, 0.f}, ab = {0.f, 0.f, 0.f, 0.f};
    float lossAcc = 0.f;
    int cnt = 0;
    while (t >= 0) {
        int tn = next[t];
        float w = pgw[t];  // broadcast; < 0 means padded
        const float4* xr = (const float4*)x + (size_t)t * (DD / 4);
        float4 xa = xr[lane], xb = xr[64 + lane];

        float dot = xa.x * ca.x + xa.y * ca.y + xa.z * ca.z + xa.w * ca.w
                  + xb.x * cb.x + xb.y * cb.y + xb.z * cb.z + xb.w * cb.w;
        float sx = xa.x * xa.x + xa.y * xa.y + xa.z * xa.z + xa.w * xa.w
                 + xb.x * xb.x + xb.y * xb.y + xb.z * xb.z + xb.w * xb.w;
        #pragma unroll
        for (int off = 32; off; off >>= 1) {
            dot += __shfl_xor(dot, off, 64);
            sx += __shfl_xor(sx, off, 64);
        }
        cnt++;  // counts include padded tokens (ref semantics)
        if (w >= 0.f) {
            float rnx = 1.0f / fmaxf(sqrtf(sx), EPS_L2);
            lossAcc += 2.f - 2.f * dot * rnx * rnc;
            aa.x += w * xa.x; aa.y += w * xa.y;
            aa.z += w * xa.z; aa.w += w * xa.w;
            ab.x += w * xb.x; ab.y += w * xb.y;
            ab.z += w * xb.z; ab.w += w * xb.w;
        }
        t = tn;
    }

    float m = 0.1f / (float)cnt;
    o[b + 0] = 0.9f * ca.x + m * aa.x;
    o[b + 1] = 0.9f * ca.y + m * aa.y;
    o[b + 2] = 0.9f * ca.z + m * aa.z;
    o[b + 3] = 0.9f * ca.w + m * aa.w;
    o[256 + b + 0] = 0.9f * cb.x + m * ab.x;
    o[256 + b + 1] = 0.9f * cb.y + m * ab.y;
    o[256 + b + 2] = 0.9f * cb.z + m * ab.z;
    o[256 + b + 3] = 0.9f * cb.w + m * ab.w;

    if (lane == 0 && lossAcc != 0.f) {
        int wv = (blockIdx.x * 256 + threadIdx.x) >> 6;
        atomicAdd(&lossPart[wv & 255], lossAcc);
    }
}

// K3: reduce 256 loss partials -> out[0].
__global__ void __launch_bounds__(256)
loss_reduce_kernel(const float* __restrict__ lossPart, float* __restrict__ out) {
    __shared__ float sm[4];
    float a = lossPart[threadIdx.x];
    #pragma unroll
    for (int off = 32; off; off >>= 1) a += __shfl_xor(a, off, 64);
    if ((threadIdx.x & 63) == 0) sm[threadIdx.x >> 6] = a;
    __syncthreads();
    if (threadIdx.x == 0) out[0] = sm[0] + sm[1] + sm[2] + sm[3];
}

extern "C" void kernel_launch(void* const* d_in, const int* in_sizes, int n_in,
                              void* d_out, int out_size, void* d_ws, size_t ws_size,
                              hipStream_t stream) {
    const float* x = (const float*)d_in[0];
    const float* p = (const float*)d_in[1];
    const int* gold = (const int*)d_in[2];
    const int* mask = (const int*)d_in[3];
    const float* cache = (const float*)d_in[4];
    float* out = (float*)d_out;
    int* head = (int*)d_ws;
    int* next = head + WS_NEXT;
    float* pgw = (float*)d_ws + WS_PGW;
    float* lossPart = (float*)d_ws + WS_LOSSP;

    hipMemsetAsync(head, 0xFF, sizeof(int) * VD, stream);  // head = -1
    build_kernel<<<NTOK / 256, 256, 0, stream>>>(gold, mask, p, head, next,
                                                 pgw, lossPart);
    row_kernel<<<ROW_BLOCKS, 256, 0, stream>>>(x, cache, head, next, pgw, out,
                                               lossPart);
    loss_reduce_kernel<<<1, 256, 0, stream>>>(lossPart, out);
}

// Round 10
// 38.399 us; speedup vs baseline: 9.7856x; 1.0063x over previous
//
#include <hip/hip_runtime.h>
#include <hip/hip_bf16.h>

#define BD 4
#define SD 2048
#define DD 512
#define VD 32000
#define NTOK (BD * SD)
#define EPS_L2 1e-12f
#define ROW_BLOCKS (VD / 4)  // one wave per row, 4 waves/block

// ws layout: [ head V int ][ next NTOK int ][ pgw NTOK f32 ][ lossPart 256 f32 ]
#define WS_NEXT VD
#define WS_PGW (VD + NTOK)
#define WS_LOSSP (VD + 2 * NTOK)

// K1 (after a 128KB memset of head to 0xFF): build per-vocab token lists,
// stash p[t,gold] (sign encodes pad), zero loss partials.
__global__ void __launch_bounds__(256)
build_kernel(const int* __restrict__ gold, const int* __restrict__ mask,
             const float* __restrict__ p, int* __restrict__ head,
             int* __restrict__ next, float* __restrict__ pgw,
             float* __restrict__ lossPart) {
    int t = blockIdx.x * 256 + threadIdx.x;
    if (blockIdx.x == 0) lossPart[threadIdx.x] = 0.f;
    int g = gold[t];
    next[t] = atomicExch(&head[g], t);
    float pg = p[(size_t)t * VD + g];
    pgw[t] = mask[t] ? -1.f : pg;  // p in [0,1); sign marks pad
}

// K2: one wave per vocab row. Single pass: copy/blend + loss.
// __launch_bounds__(256,8): push 8 waves/EU (32/CU) — working set is
// LLC-resident so the kernel is latency-bound, not HBM-BW-bound.
// NO __threadfence here (R8: per-block fences = XCD L2 writeback, 302us).
__global__ void __launch_bounds__(256, 8)
row_kernel(const float* __restrict__ x, const float* __restrict__ cache,
           const int* __restrict__ head, const int* __restrict__ next,
           const float* __restrict__ pgw, float* __restrict__ out,
           float* __restrict__ lossPart) {
    int row = blockIdx.x * 4 + (threadIdx.x >> 6);
    int lane = threadIdx.x & 63;
    const float4* cr = (const float4*)cache + (size_t)row * (DD / 4);
    float4 ca = cr[lane], cb = cr[64 + lane];
    float* o = out + 1 + (size_t)row * DD;
    int b = lane * 4;
    int t = head[row];

    if (t < 0) {  // untouched row: passthrough copy
        o[b + 0] = ca.x; o[b + 1] = ca.y; o[b + 2] = ca.z; o[b + 3] = ca.w;
        o[256 + b + 0] = cb.x; o[256 + b + 1] = cb.y;
        o[256 + b + 2] = cb.z; o[256 + b + 3] = cb.w;
        return;
    }

    float sc = ca.x * ca.x + ca.y * ca.y + ca.z * ca.z + ca.w * ca.w
             + cb.x * cb.x + cb.y * cb.y + cb.z * cb.z + cb.w * cb.w;
    #pragma unroll
    for (int off = 32; off; off >>= 1) sc += __shfl_xor(sc, off, 64);
    float rnc = 1.0f / fmaxf(sqrtf(sc), EPS_L2);

    float4 aa = {0.f, 0.f, 0.f, 0.f}, ab = {0.f, 0.f, 0.f, 0.f};
    float lossAcc = 0.f;
    int cnt = 0;
    while (t >= 0) {
        int tn = next[t];
        float w = pgw[t];  // broadcast; < 0 means padded
        const float4* xr = (const float4*)x + (size_t)t * (DD / 4);
        float4 xa = xr[lane], xb = xr[64 + lane];

        float dot = xa.x * ca.x + xa.y * ca.y + xa.z * ca.z + xa.w * ca.w
                  + xb.x * cb.x + xb.y * cb.y + xb.z * cb.z + xb.w * cb.w;
        float sx = xa.x * xa.x + xa.y * xa.y + xa.z * xa.z + xa.w * xa.w
                 + xb.x * xb.x + xb.y * xb.y + xb.z * xb.z + xb.w * xb.w;
        #pragma unroll
        for (int off = 32; off; off >>= 1) {
            dot += __shfl_xor(dot, off, 64);
            sx += __shfl_xor(sx, off, 64);
        }
        cnt++;  // counts include padded tokens (ref semantics)
        if (w >= 0.f) {
            float rnx = 1.0f / fmaxf(sqrtf(sx), EPS_L2);
            lossAcc += 2.f - 2.f * dot * rnx * rnc;
            aa.x += w * xa.x; aa.y += w * xa.y;
            aa.z += w * xa.z; aa.w += w * xa.w;
            ab.x += w * xb.x; ab.y += w * xb.y;
            ab.z += w * xb.z; ab.w += w * xb.w;
        }
        t = tn;
    }

    float m = 0.1f / (float)cnt;
    o[b + 0] = 0.9f * ca.x + m * aa.x;
    o[b + 1] = 0.9f * ca.y + m * aa.y;
    o[b + 2] = 0.9f * ca.z + m * aa.z;
    o[b + 3] = 0.9f * ca.w + m * aa.w;
    o[256 + b + 0] = 0.9f * cb.x + m * ab.x;
    o[256 + b + 1] = 0.9f * cb.y + m * ab.y;
    o[256 + b + 2] = 0.9f * cb.z + m * ab.z;
    o[256 + b + 3] = 0.9f * cb.w + m * ab.w;

    if (lane == 0 && lossAcc != 0.f) {
        int wv = (blockIdx.x * 256 + threadIdx.x) >> 6;
        atomicAdd(&lossPart[wv & 255], lossAcc);
    }
}

// K3: reduce 256 loss partials -> out[0].
__global__ void __launch_bounds__(256)
loss_reduce_kernel(const float* __restrict__ lossPart, float* __restrict__ out) {
    __shared__ float sm[4];
    float a = lossPart[threadIdx.x];
    #pragma unroll
    for (int off = 32; off; off >>= 1) a += __shfl_xor(a, off, 64);
    if ((threadIdx.x & 63) == 0) sm[threadIdx.x >> 6] = a;
    __syncthreads();
    if (threadIdx.x == 0) out[0] = sm[0] + sm[1] + sm[2] + sm[3];
}

extern "C" void kernel_launch(void* const* d_in, const int* in_sizes, int n_in,
                              void* d_out, int out_size, void* d_ws, size_t ws_size,
                              hipStream_t stream) {
    const float* x = (const float*)d_in[0];
    const float* p = (const float*)d_in[1];
    const int* gold = (const int*)d_in[2];
    const int* mask = (const int*)d_in[3];
    const float* cache = (const float*)d_in[4];
    float* out = (float*)d_out;
    int* head = (int*)d_ws;
    int* next = head + WS_NEXT;
    float* pgw = (float*)d_ws + WS_PGW;
    float* lossPart = (float*)d_ws + WS_LOSSP;

    hipMemsetAsync(head, 0xFF, sizeof(int) * VD, stream);  // head = -1
    build_kernel<<<NTOK / 256, 256, 0, stream>>>(gold, mask, p, head, next,
                                                 pgw, lossPart);
    row_kernel<<<ROW_BLOCKS, 256, 0, stream>>>(x, cache, head, next, pgw, out,
                                               lossPart);
    loss_reduce_kernel<<<1, 256, 0, stream>>>(lossPart, out);
}